// Round 4
// baseline (11325.609 us; speedup 1.0000x reference)
//
#include <hip/hip_runtime.h>
#include <math.h>

#define NPTS 8192
#define BATCH 2
#define MCENT 4096
#define FD 64
#define SD 5
#define AD 256

typedef float f32x2 __attribute__((ext_vector_type(2)));

// ----------------------------- FPS ---------------------------------
// One block per batch. 1024 threads, each owns 8 points as 4 float2-pairs.
// Key fix (r3): coords are passed through an empty asm() after the initial
// load — without this, hipcc sinks the (restrict/const) global loads into
// the serial loop and re-reads ~160KB from L2 every iteration (r1/r2
// counters: VGPR_Count=64 < live state, dur pinned at ~2us/iter).
// Single barrier per iteration via parity double-buffered LDS slots.
#define FPS_T 1024
#define NPAIR 4
__global__ __launch_bounds__(FPS_T, 1) void fps_kernel(const float* __restrict__ spatial,
                                                       int* __restrict__ idxs)
{
#pragma clang fp contract(off)
    const int b = blockIdx.x;
    const int tid = threadIdx.x;
    const float* sp = spatial + (size_t)b * NPTS * SD;
    int* out = idxs + (size_t)b * MCENT;

    // pc[c][q]: coord c of points (tid + 2q*1024, tid + (2q+1)*1024)
    f32x2 pc[SD][NPAIR];
    f32x2 d2[NPAIR];
#pragma unroll
    for (int q = 0; q < NPAIR; ++q) {
        const int p0 = tid + ((2 * q) << 10);
        const int p1 = tid + ((2 * q + 1) << 10);
#pragma unroll
        for (int c = 0; c < SD; ++c) {
            pc[c][q].x = sp[(size_t)p0 * SD + c];
            pc[c][q].y = sp[(size_t)p1 * SD + c];
        }
        d2[q].x = INFINITY; d2[q].y = INFINITY;
    }
    // Pin coords in VGPRs: opaque producer, compiler cannot re-load them.
#pragma unroll
    for (int q = 0; q < NPAIR; ++q)
#pragma unroll
        for (int c = 0; c < SD; ++c)
            asm volatile("" : "+v"(pc[c][q].x), "+v"(pc[c][q].y));

    if (tid == 0) { d2[0].x = -INFINITY; out[0] = 0; }  // point 0 pre-selected

    __shared__ float sval[2][16];
    __shared__ int   sidx[2][16];

    float l0 = sp[0], l1 = sp[1], l2 = sp[2], l3 = sp[3], l4 = sp[4];

    const int lane = tid & 63;
    const int wid  = tid >> 6;            // 0..15

    for (int i = 1; i < MCENT; ++i) {
        const int par = i & 1;
        const f32x2 L0 = {l0, l0}, L1 = {l1, l1}, L2 = {l2, l2},
                    L3 = {l3, l3}, L4 = {l4, l4};
        float bv = -INFINITY; int bi = 0x7fffffff;
#pragma unroll
        for (int q = 0; q < NPAIR; ++q) {
            // exact numpy order per component: (((d0^2+d1^2)+d2^2)+d3^2)+d4^2
            f32x2 dx = pc[0][q] - L0; f32x2 s = dx * dx;
            f32x2 dy = pc[1][q] - L1; s = s + dy * dy;
            f32x2 dz = pc[2][q] - L2; s = s + dz * dz;
            f32x2 dw = pc[3][q] - L3; s = s + dw * dw;
            f32x2 du = pc[4][q] - L4; s = s + du * du;
            f32x2 nd;
            nd.x = fminf(d2[q].x, s.x);   // -inf mask is absorbing
            nd.y = fminf(d2[q].y, s.y);
            d2[q] = nd;
            const bool hi = nd.y > nd.x;                   // tie -> .x (lower idx)
            const float pv = hi ? nd.y : nd.x;
            const int  pidx = tid + ((2 * q + (hi ? 1 : 0)) << 10);
            if (pv > bv) { bv = pv; bi = pidx; }           // q asc => idx asc
        }
        // wave butterfly argmax, lowest-index tie-break
#pragma unroll
        for (int off = 1; off < 64; off <<= 1) {
            const float ov = __shfl_xor(bv, off, 64);
            const int   oi = __shfl_xor(bi, off, 64);
            if (ov > bv || (ov == bv && oi < bi)) { bv = ov; bi = oi; }
        }
        if (lane == 0) { sval[par][wid] = bv; sidx[par][wid] = bi; }
        __syncthreads();
        // all threads redundantly reduce the 16 wave results (no 2nd barrier;
        // parity slots make next iteration's writes race-free)
        float v = sval[par][0]; int ix = sidx[par][0];
#pragma unroll
        for (int w = 1; w < 16; ++w) {
            const float wv = sval[par][w]; const int wi = sidx[par][w];
            if (wv > v || (wv == v && wi < ix)) { v = wv; ix = wi; }
        }
        const int sel = ix;
        // mask the selected point (static indices only — no scratch)
        const int dlt = sel - tid;
#pragma unroll
        for (int q = 0; q < NPAIR; ++q) {
            if (dlt == ((2 * q) << 10))     d2[q].x = -INFINITY;
            if (dlt == ((2 * q + 1) << 10)) d2[q].y = -INFINITY;
        }
        if (tid == 0) out[i] = sel;
        // uniform (SGPR) broadcast reload of the new pivot's coords
        const int selu = __builtin_amdgcn_readfirstlane(sel);
        const float* lp = sp + (size_t)selu * SD;
        l0 = lp[0]; l1 = lp[1]; l2 = lp[2]; l3 = lp[3]; l4 = lp[4];
    }
}

// ----------------------------- KNN ---------------------------------
// Stable top-4 smallest (d, idx) per centroid; self forced to -1.0.
// Block: 512 threads = 64 centroids x 8 partial scanners. Grid: B*64.
#define KPARTS 8
__global__ __launch_bounds__(512) void knn_kernel(const float* __restrict__ spatial,
                                                  const int* __restrict__ idxs,
                                                  int* __restrict__ nn)
{
#pragma clang fp contract(off)
    const int blk = blockIdx.x;
    const int b = blk >> 6;
    const int grp = blk & 63;
    const int tid = threadIdx.x;
    const int lc = tid >> 3;      // local centroid 0..63
    const int part = tid & 7;
    const float* sp = spatial + (size_t)b * NPTS * SD;
    const int cid = (grp << 6) + lc;
    const int ctr = idxs[b * MCENT + cid];
    const float c0 = sp[(size_t)ctr * SD + 0], c1 = sp[(size_t)ctr * SD + 1],
                c2 = sp[(size_t)ctr * SD + 2], c3 = sp[(size_t)ctr * SD + 3],
                c4 = sp[(size_t)ctr * SD + 4];

    float bd[4] = {INFINITY, INFINITY, INFINITY, INFINITY};
    int   bi[4] = {0x7fffffff, 0x7fffffff, 0x7fffffff, 0x7fffffff};

    __shared__ float tile[2048 * SD];            // 40 KB
    __shared__ float md[64][KPARTS][4];          // 8 KB
    __shared__ int   mi[64][KPARTS][4];          // 8 KB

    for (int t0 = 0; t0 < NPTS; t0 += 2048) {
        __syncthreads();
        for (int e = tid; e < 2048 * SD; e += 512) tile[e] = sp[(size_t)t0 * SD + e];
        __syncthreads();
        for (int p = part; p < 2048; p += KPARTS) {
            const int gp = t0 + p;
            float x0 = tile[p * SD + 0] - c0; float d = x0 * x0;
            float x1 = tile[p * SD + 1] - c1; d = d + x1 * x1;
            float x2 = tile[p * SD + 2] - c2; d = d + x2 * x2;
            float x3 = tile[p * SD + 3] - c3; d = d + x3 * x3;
            float x4 = tile[p * SD + 4] - c4; d = d + x4 * x4;
            if (gp == ctr) d = -1.0f;
            const bool lt0 = (d < bd[0]) || (d == bd[0] && gp < bi[0]);
            const bool lt1 = (d < bd[1]) || (d == bd[1] && gp < bi[1]);
            const bool lt2 = (d < bd[2]) || (d == bd[2] && gp < bi[2]);
            const bool lt3 = (d < bd[3]) || (d == bd[3] && gp < bi[3]);
            if (lt3) {
                bd[3] = lt2 ? bd[2] : d;  bi[3] = lt2 ? bi[2] : gp;
                if (lt2) {
                    bd[2] = lt1 ? bd[1] : d;  bi[2] = lt1 ? bi[1] : gp;
                    if (lt1) {
                        bd[1] = lt0 ? bd[0] : d;  bi[1] = lt0 ? bi[0] : gp;
                        if (lt0) { bd[0] = d; bi[0] = gp; }
                    }
                }
            }
        }
    }
#pragma unroll
    for (int s = 0; s < 4; ++s) { md[lc][part][s] = bd[s]; mi[lc][part][s] = bi[s]; }
    __syncthreads();
    if (part == 0) {
        int ptr[KPARTS] = {0, 0, 0, 0, 0, 0, 0, 0};
        int outi[4];
        for (int s = 0; s < 4; ++s) {
            float bestd = INFINITY; int besti = 0x7fffffff; int bl = 0;
            for (int l = 0; l < KPARTS; ++l) {
                const int pl = ptr[l];
                if (pl < 4) {
                    const float dv = md[lc][l][pl];
                    const int   iv = mi[lc][l][pl];
                    if (dv < bestd || (dv == bestd && iv < besti)) { bestd = dv; besti = iv; bl = l; }
                }
            }
            ptr[bl]++;
            outi[s] = besti;
        }
        int* o = nn + ((size_t)b * MCENT + cid) * 3;
        o[0] = outi[1]; o[1] = outi[2]; o[2] = outi[3];   // skip self
    }
}

// --------------------------- gather --------------------------------
// Builds A_sa [B*M*3, 69] = [nbr_feat | rel] and writes centroids to d_out.
__global__ __launch_bounds__(256) void gather_kernel(const float* __restrict__ x,
                                                     const float* __restrict__ spatial,
                                                     const int* __restrict__ idxs,
                                                     const int* __restrict__ nn,
                                                     float* __restrict__ Asa,
                                                     float* __restrict__ cent_out)
{
    const int r = blockIdx.x;           // 0..B*M-1
    const int b = r >> 12;
    const int tid = threadIdx.x;
    const float* sp = spatial + (size_t)b * NPTS * SD;
    const float* xb = x + (size_t)b * NPTS * FD;
    const int ctr = idxs[r];
    __shared__ int nnk[3];
    if (tid < 3) nnk[tid] = nn[(size_t)r * 3 + tid];
    __syncthreads();
    if (tid < 192) {
        const int k = tid >> 6, c = tid & 63;
        Asa[((size_t)r * 3 + k) * 69 + c] = xb[(size_t)nnk[k] * FD + c];
    } else if (tid < 207) {
        const int e = tid - 192; const int k = e / 5, c = e % 5;
        Asa[((size_t)r * 3 + k) * 69 + 64 + c] =
            sp[(size_t)nnk[k] * SD + c] - sp[(size_t)ctr * SD + c];
    } else if (tid < 212) {
        const int c = tid - 207;
        cent_out[(size_t)r * SD + c] = sp[(size_t)ctr * SD + c];
    }
}

// ---------------------------- GEMM ---------------------------------
// C[M,N] = A[M,K] @ B[K,N] + bias ; EPI: 0 none, 1 relu, 2 +extra
template<int EPI>
__global__ __launch_bounds__(256) void gemm_kernel(const float* __restrict__ A,
                                                   const float* __restrict__ Bw,
                                                   const float* __restrict__ bias,
                                                   const float* __restrict__ extra,
                                                   float* __restrict__ C,
                                                   int Mrows, int Kdim, int Ncols)
{
    __shared__ float As[16][64];
    __shared__ float Bs[16][64];
    const int tid = threadIdx.x;
    const int tx = tid & 15, ty = tid >> 4;
    const int m0 = blockIdx.y << 6, n0 = blockIdx.x << 6;
    float acc[4][4] = {};
    for (int k0 = 0; k0 < Kdim; k0 += 16) {
#pragma unroll
        for (int i = 0; i < 4; ++i) {
            const int e = tid + (i << 8);
            const int col = e & 63, row = e >> 6;
            const int gk = k0 + row;
            As[row][col] = (gk < Kdim) ? A[(size_t)(m0 + col) * Kdim + gk] : 0.f;
            Bs[row][col] = (gk < Kdim) ? Bw[(size_t)gk * Ncols + n0 + col] : 0.f;
        }
        __syncthreads();
#pragma unroll
        for (int kk = 0; kk < 16; ++kk) {
            const float4 ra = *(const float4*)(&As[kk][ty << 2]);
            const float4 rb = *(const float4*)(&Bs[kk][tx << 2]);
            const float av[4] = {ra.x, ra.y, ra.z, ra.w};
            const float bv[4] = {rb.x, rb.y, rb.z, rb.w};
#pragma unroll
            for (int ii = 0; ii < 4; ++ii)
#pragma unroll
                for (int jj = 0; jj < 4; ++jj)
                    acc[ii][jj] = fmaf(av[ii], bv[jj], acc[ii][jj]);
        }
        __syncthreads();
    }
#pragma unroll
    for (int ii = 0; ii < 4; ++ii) {
        const int gm = m0 + (ty << 2) + ii;
#pragma unroll
        for (int jj = 0; jj < 4; ++jj) {
            const int gn = n0 + (tx << 2) + jj;
            float v = acc[ii][jj] + bias[gn];
            if (EPI == 1) v = fmaxf(v, 0.f);
            if (EPI == 2) v += extra[(size_t)gm * Ncols + gn];
            C[(size_t)gm * Ncols + gn] = v;
        }
    }
}

// ------------------------- BN + max over k -------------------------
__global__ __launch_bounds__(256) void bnmax_kernel(const float* __restrict__ h,
                                                    const float* __restrict__ g,
                                                    const float* __restrict__ be,
                                                    const float* __restrict__ mu,
                                                    const float* __restrict__ var,
                                                    float* __restrict__ f)
{
    const int r = blockIdx.x;          // 0..B*M-1
    const int m = r & (MCENT - 1);
    const int c = threadIdx.x;
    const float inv = g[m] / sqrtf(var[m] + 1e-5f);
    const float shift = be[m] - mu[m] * inv;
    const size_t base = (size_t)r * 3 * AD + c;
    const float v0 = fmaxf(h[base] * inv + shift, 0.f);
    const float v1 = fmaxf(h[base + AD] * inv + shift, 0.f);
    const float v2 = fmaxf(h[base + 2 * AD] * inv + shift, 0.f);
    f[(size_t)r * AD + c] = fmaxf(v0, fmaxf(v1, v2));
}

// ------------------------- W_q - W_k precompute --------------------
__global__ void wdiff_kernel(const float* __restrict__ Wq, const float* __restrict__ bq,
                             const float* __restrict__ Wk, const float* __restrict__ bk,
                             float* __restrict__ Wqk, float* __restrict__ bqk)
{
    const int i = blockIdx.x * blockDim.x + threadIdx.x;
    if (i < AD * AD) Wqk[i] = Wq[i] - Wk[i];
    if (i < AD) bqk[i] = bq[i] - bk[i];
}

// --------------------------- softmax -------------------------------
__global__ __launch_bounds__(256) void softmax_kernel(float* __restrict__ s)
{
    const int r = blockIdx.x;
    const int c = threadIdx.x;
    const int lane = c & 63, w = c >> 6;
    float v = s[(size_t)r * AD + c];
    float mx = v;
#pragma unroll
    for (int off = 1; off < 64; off <<= 1) mx = fmaxf(mx, __shfl_xor(mx, off, 64));
    __shared__ float sm[4];
    __shared__ float ss[4];
    if (lane == 0) sm[w] = mx;
    __syncthreads();
    mx = fmaxf(fmaxf(sm[0], sm[1]), fmaxf(sm[2], sm[3]));
    const float e = expf(v - mx);
    float sum = e;
#pragma unroll
    for (int off = 1; off < 64; off <<= 1) sum += __shfl_xor(sum, off, 64);
    if (lane == 0) ss[w] = sum;
    __syncthreads();
    sum = ss[0] + ss[1] + ss[2] + ss[3];
    s[(size_t)r * AD + c] = e / sum;
}

// --------------------------- w * v ---------------------------------
__global__ void mul_kernel(const float* __restrict__ w, float* __restrict__ v, int n)
{
    for (int i = blockIdx.x * blockDim.x + threadIdx.x; i < n; i += gridDim.x * blockDim.x)
        v[i] = w[i] * v[i];
}

// ---------------------------- launch -------------------------------
extern "C" void kernel_launch(void* const* d_in, const int* in_sizes, int n_in,
                              void* d_out, int out_size, void* d_ws, size_t ws_size,
                              hipStream_t stream)
{
    const float* x       = (const float*)d_in[0];
    const float* spatial = (const float*)d_in[1];
    const float* W_sa  = (const float*)d_in[2];
    const float* b_sa  = (const float*)d_in[3];
    const float* gamma = (const float*)d_in[4];
    const float* beta  = (const float*)d_in[5];
    const float* mean  = (const float*)d_in[6];
    const float* var   = (const float*)d_in[7];
    const float* W_in  = (const float*)d_in[8];
    const float* b_in  = (const float*)d_in[9];
    const float* W_q   = (const float*)d_in[10];
    const float* b_q   = (const float*)d_in[11];
    const float* W_k   = (const float*)d_in[12];
    const float* b_k   = (const float*)d_in[13];
    const float* W_v   = (const float*)d_in[14];
    const float* b_v   = (const float*)d_in[15];
    const float* W_w1  = (const float*)d_in[16];
    const float* b_w1  = (const float*)d_in[17];
    const float* W_w2  = (const float*)d_in[18];
    const float* b_w2  = (const float*)d_in[19];
    const float* W_out = (const float*)d_in[20];
    const float* b_out = (const float*)d_in[21];

    float* ws = (float*)d_ws;
    size_t o = 0;
    int* idxs = (int*)(ws + o); o += BATCH * MCENT;                 // 8192
    int* nn   = (int*)(ws + o); o += BATCH * MCENT * 3;             // 24576
    float* Wqk = ws + o; o += AD * AD;
    float* bqk = ws + o; o += AD;
    float* Asa = ws + o; o += (size_t)BATCH * MCENT * 3 * 69;       // 1695744
    float* h   = ws + o; o += (size_t)BATCH * MCENT * 3 * AD;       // 6291456
    float* f   = ws + o; o += (size_t)BATCH * MCENT * AD;           // 2097152
    float* u   = ws + o; o += (size_t)BATCH * MCENT * AD;           // 2097152
    // reuse h region after bnmax: t, qd, v ; reuse qd region for sgm
    float* t   = h;
    float* qd  = h + (size_t)BATCH * MCENT * AD;
    float* v   = h + (size_t)2 * BATCH * MCENT * AD;
    float* sgm = qd;

    float* outp = (float*)d_out;
    float* cent = outp + (size_t)BATCH * MCENT * AD;

    const int ROWS = BATCH * MCENT;          // 8192
    const int HROWS = ROWS * 3;              // 24576

    fps_kernel<<<BATCH, FPS_T, 0, stream>>>(spatial, idxs);
    knn_kernel<<<BATCH * 64, 512, 0, stream>>>(spatial, idxs, nn);
    gather_kernel<<<ROWS, 256, 0, stream>>>(x, spatial, idxs, nn, Asa, cent);
    wdiff_kernel<<<(AD * AD + 255) / 256, 256, 0, stream>>>(W_q, b_q, W_k, b_k, Wqk, bqk);

    gemm_kernel<0><<<dim3(AD / 64, HROWS / 64), 256, 0, stream>>>(Asa, W_sa, b_sa, nullptr, h, HROWS, 69, AD);
    bnmax_kernel<<<ROWS, 256, 0, stream>>>(h, gamma, beta, mean, var, f);
    gemm_kernel<0><<<dim3(AD / 64, ROWS / 64), 256, 0, stream>>>(f, W_in, b_in, nullptr, t, ROWS, AD, AD);
    gemm_kernel<0><<<dim3(AD / 64, ROWS / 64), 256, 0, stream>>>(t, Wqk, bqk, nullptr, qd, ROWS, AD, AD);
    gemm_kernel<0><<<dim3(AD / 64, ROWS / 64), 256, 0, stream>>>(t, W_v, b_v, nullptr, v, ROWS, AD, AD);
    gemm_kernel<1><<<dim3(AD / 64, ROWS / 64), 256, 0, stream>>>(qd, W_w1, b_w1, nullptr, u, ROWS, AD, AD);
    gemm_kernel<0><<<dim3(AD / 64, ROWS / 64), 256, 0, stream>>>(u, W_w2, b_w2, nullptr, sgm, ROWS, AD, AD);
    softmax_kernel<<<ROWS, 256, 0, stream>>>(sgm);
    mul_kernel<<<2048, 256, 0, stream>>>(sgm, v, ROWS * AD);
    gemm_kernel<2><<<dim3(AD / 64, ROWS / 64), 256, 0, stream>>>(v, W_out, b_out, f, outp, ROWS, AD, AD);
}

// Round 5
// 8134.490 us; speedup vs baseline: 1.3923x; 1.3923x over previous
//
#include <hip/hip_runtime.h>
#include <math.h>

#define NPTS 8192
#define BATCH 2
#define MCENT 4096
#define FD 64
#define SD 5
#define AD 256

typedef float f32x2 __attribute__((ext_vector_type(2)));

// ----------------------------- FPS ---------------------------------
// One block per batch, 1024 threads, 8 points/thread.
// r4 structure: coords c0..c3 of ALL points live in 128KB static LDS
// (gfx950 allows >64KB/workgroup); c4 + running dists live in registers
// (~50 VGPR — under the allocator's default 64 budget, so no remat/spill;
// r0-r3 showed the allocator re-reads or spills any state beyond that
// budget, costing ~2900cy/iter of L2 traffic).
// Argmax in u64 key space: (bits(d)+2)<<32 | ~idx  =>  max() == numpy
// argmax with lowest-index tie-break. 2 barriers/iteration.
#define FPS_T 1024
#define FPS_PAIRS 4

__device__ __forceinline__ unsigned long long fps_key(float d, int idx) {
    const unsigned ks = (d == -INFINITY) ? 1u : (__float_as_uint(d) + 2u);
    return ((unsigned long long)ks << 32) | (unsigned)(~idx);
}

__global__ __launch_bounds__(FPS_T) void fps_kernel(const float* __restrict__ spatial,
                                                    int* __restrict__ idxs)
{
#pragma clang fp contract(off)
    const int b = blockIdx.x;
    const int tid = threadIdx.x;
    const float* sp = spatial + (size_t)b * NPTS * SD;
    int* out = idxs + (size_t)b * MCENT;

    __shared__ float cs0[NPTS];              // 32 KB
    __shared__ float cs1[NPTS];              // 32 KB
    __shared__ float cs2[NPTS];              // 32 KB
    __shared__ float cs3[NPTS];              // 32 KB
    __shared__ unsigned long long skey[16];
    __shared__ unsigned long long gkey;

    // cooperative LDS fill of c0..c3 (SoA: bank = pt%32, 2-way = free)
    for (int e = tid; e < NPTS; e += FPS_T) {
        cs0[e] = sp[(size_t)e * SD + 0];
        cs1[e] = sp[(size_t)e * SD + 1];
        cs2[e] = sp[(size_t)e * SD + 2];
        cs3[e] = sp[(size_t)e * SD + 3];
    }
    f32x2 c4p[FPS_PAIRS];
    f32x2 d2[FPS_PAIRS];
#pragma unroll
    for (int q = 0; q < FPS_PAIRS; ++q) {
        const int p0 = tid + ((2 * q) << 10);
        const int p1 = tid + ((2 * q + 1) << 10);
        c4p[q].x = sp[(size_t)p0 * SD + 4];
        c4p[q].y = sp[(size_t)p1 * SD + 4];
        d2[q].x = INFINITY; d2[q].y = INFINITY;
    }
    // pin only c4 (8 regs, far under budget -> no spill pathology)
#pragma unroll
    for (int q = 0; q < FPS_PAIRS; ++q)
        asm volatile("" : "+v"(c4p[q].x), "+v"(c4p[q].y));

    if (tid == 0) { d2[0].x = -INFINITY; out[0] = 0; }   // point 0 pre-selected

    float l0 = sp[0], l1 = sp[1], l2 = sp[2], l3 = sp[3], l4 = sp[4];
    const int lane = tid & 63, wid = tid >> 6;
    __syncthreads();

    for (int i = 1; i < MCENT; ++i) {
        const f32x2 L0 = {l0, l0}, L1 = {l1, l1}, L2 = {l2, l2},
                    L3 = {l3, l3}, L4 = {l4, l4};
        unsigned long long key = 0;
#pragma unroll
        for (int q = 0; q < FPS_PAIRS; ++q) {
            const int p0 = tid + ((2 * q) << 10);
            const int p1 = p0 + 1024;
            const f32x2 v0 = { cs0[p0], cs0[p1] };
            const f32x2 v1 = { cs1[p0], cs1[p1] };
            const f32x2 v2 = { cs2[p0], cs2[p1] };
            const f32x2 v3 = { cs3[p0], cs3[p1] };
            // exact numpy order: ((((d0^2+d1^2)+d2^2)+d3^2)+d4^2
            f32x2 dx = v0 - L0;     f32x2 s = dx * dx;
            f32x2 dy = v1 - L1;     s = s + dy * dy;
            f32x2 dz = v2 - L2;     s = s + dz * dz;
            f32x2 dw = v3 - L3;     s = s + dw * dw;
            f32x2 du = c4p[q] - L4; s = s + du * du;
            f32x2 nd;
            nd.x = fminf(d2[q].x, s.x);   // -inf mask is absorbing
            nd.y = fminf(d2[q].y, s.y);
            d2[q] = nd;
            const unsigned long long k0 = fps_key(nd.x, p0);
            const unsigned long long k1 = fps_key(nd.y, p1);
            if (k0 > key) key = k0;
            if (k1 > key) key = k1;
        }
        // wave butterfly max over u64 keys
#pragma unroll
        for (int off = 1; off < 64; off <<= 1) {
            const unsigned long long o = __shfl_xor(key, off, 64);
            if (o > key) key = o;
        }
        if (lane == 0) skey[wid] = key;
        __syncthreads();
        if (tid == 0) {
            unsigned long long bk = skey[0];
#pragma unroll
            for (int w = 1; w < 16; ++w) if (skey[w] > bk) bk = skey[w];
            gkey = bk;
            out[i] = (int)(~(unsigned)bk);
        }
        __syncthreads();
        const int gidx = (int)(~(unsigned)gkey);
        // mask the selected point (static indices only)
        const int dlt = gidx - tid;
#pragma unroll
        for (int q = 0; q < FPS_PAIRS; ++q) {
            if (dlt == ((2 * q) << 10))     d2[q].x = -INFINITY;
            if (dlt == ((2 * q + 1) << 10)) d2[q].y = -INFINITY;
        }
        // next pivot: c0..c3 from LDS (uniform -> broadcast), c4 scalar global
        const int su = __builtin_amdgcn_readfirstlane(gidx);
        l0 = cs0[su]; l1 = cs1[su]; l2 = cs2[su]; l3 = cs3[su];
        l4 = sp[(size_t)su * SD + 4];
    }
}

// ----------------------------- KNN ---------------------------------
// Stable top-4 smallest (d, idx) per centroid; self forced to -1.0.
// Block: 512 threads = 64 centroids x 8 partial scanners. Grid: B*64.
#define KPARTS 8
__global__ __launch_bounds__(512) void knn_kernel(const float* __restrict__ spatial,
                                                  const int* __restrict__ idxs,
                                                  int* __restrict__ nn)
{
#pragma clang fp contract(off)
    const int blk = blockIdx.x;
    const int b = blk >> 6;
    const int grp = blk & 63;
    const int tid = threadIdx.x;
    const int lc = tid >> 3;      // local centroid 0..63
    const int part = tid & 7;
    const float* sp = spatial + (size_t)b * NPTS * SD;
    const int cid = (grp << 6) + lc;
    const int ctr = idxs[b * MCENT + cid];
    const float c0 = sp[(size_t)ctr * SD + 0], c1 = sp[(size_t)ctr * SD + 1],
                c2 = sp[(size_t)ctr * SD + 2], c3 = sp[(size_t)ctr * SD + 3],
                c4 = sp[(size_t)ctr * SD + 4];

    float bd[4] = {INFINITY, INFINITY, INFINITY, INFINITY};
    int   bi[4] = {0x7fffffff, 0x7fffffff, 0x7fffffff, 0x7fffffff};

    __shared__ float tile[2048 * SD];            // 40 KB
    __shared__ float md[64][KPARTS][4];          // 8 KB
    __shared__ int   mi[64][KPARTS][4];          // 8 KB

    for (int t0 = 0; t0 < NPTS; t0 += 2048) {
        __syncthreads();
        for (int e = tid; e < 2048 * SD; e += 512) tile[e] = sp[(size_t)t0 * SD + e];
        __syncthreads();
        for (int p = part; p < 2048; p += KPARTS) {
            const int gp = t0 + p;
            float x0 = tile[p * SD + 0] - c0; float d = x0 * x0;
            float x1 = tile[p * SD + 1] - c1; d = d + x1 * x1;
            float x2 = tile[p * SD + 2] - c2; d = d + x2 * x2;
            float x3 = tile[p * SD + 3] - c3; d = d + x3 * x3;
            float x4 = tile[p * SD + 4] - c4; d = d + x4 * x4;
            if (gp == ctr) d = -1.0f;
            const bool lt0 = (d < bd[0]) || (d == bd[0] && gp < bi[0]);
            const bool lt1 = (d < bd[1]) || (d == bd[1] && gp < bi[1]);
            const bool lt2 = (d < bd[2]) || (d == bd[2] && gp < bi[2]);
            const bool lt3 = (d < bd[3]) || (d == bd[3] && gp < bi[3]);
            if (lt3) {
                bd[3] = lt2 ? bd[2] : d;  bi[3] = lt2 ? bi[2] : gp;
                if (lt2) {
                    bd[2] = lt1 ? bd[1] : d;  bi[2] = lt1 ? bi[1] : gp;
                    if (lt1) {
                        bd[1] = lt0 ? bd[0] : d;  bi[1] = lt0 ? bi[0] : gp;
                        if (lt0) { bd[0] = d; bi[0] = gp; }
                    }
                }
            }
        }
    }
#pragma unroll
    for (int s = 0; s < 4; ++s) { md[lc][part][s] = bd[s]; mi[lc][part][s] = bi[s]; }
    __syncthreads();
    if (part == 0) {
        int ptr[KPARTS] = {0, 0, 0, 0, 0, 0, 0, 0};
        int outi[4];
        for (int s = 0; s < 4; ++s) {
            float bestd = INFINITY; int besti = 0x7fffffff; int bl = 0;
            for (int l = 0; l < KPARTS; ++l) {
                const int pl = ptr[l];
                if (pl < 4) {
                    const float dv = md[lc][l][pl];
                    const int   iv = mi[lc][l][pl];
                    if (dv < bestd || (dv == bestd && iv < besti)) { bestd = dv; besti = iv; bl = l; }
                }
            }
            ptr[bl]++;
            outi[s] = besti;
        }
        int* o = nn + ((size_t)b * MCENT + cid) * 3;
        o[0] = outi[1]; o[1] = outi[2]; o[2] = outi[3];   // skip self
    }
}

// --------------------------- gather --------------------------------
// Builds A_sa [B*M*3, 69] = [nbr_feat | rel] and writes centroids to d_out.
__global__ __launch_bounds__(256) void gather_kernel(const float* __restrict__ x,
                                                     const float* __restrict__ spatial,
                                                     const int* __restrict__ idxs,
                                                     const int* __restrict__ nn,
                                                     float* __restrict__ Asa,
                                                     float* __restrict__ cent_out)
{
    const int r = blockIdx.x;           // 0..B*M-1
    const int b = r >> 12;
    const int tid = threadIdx.x;
    const float* sp = spatial + (size_t)b * NPTS * SD;
    const float* xb = x + (size_t)b * NPTS * FD;
    const int ctr = idxs[r];
    __shared__ int nnk[3];
    if (tid < 3) nnk[tid] = nn[(size_t)r * 3 + tid];
    __syncthreads();
    if (tid < 192) {
        const int k = tid >> 6, c = tid & 63;
        Asa[((size_t)r * 3 + k) * 69 + c] = xb[(size_t)nnk[k] * FD + c];
    } else if (tid < 207) {
        const int e = tid - 192; const int k = e / 5, c = e % 5;
        Asa[((size_t)r * 3 + k) * 69 + 64 + c] =
            sp[(size_t)nnk[k] * SD + c] - sp[(size_t)ctr * SD + c];
    } else if (tid < 212) {
        const int c = tid - 207;
        cent_out[(size_t)r * SD + c] = sp[(size_t)ctr * SD + c];
    }
}

// ---------------------------- GEMM ---------------------------------
// C[M,N] = A[M,K] @ B[K,N] + bias ; EPI: 0 none, 1 relu, 2 +extra
template<int EPI>
__global__ __launch_bounds__(256) void gemm_kernel(const float* __restrict__ A,
                                                   const float* __restrict__ Bw,
                                                   const float* __restrict__ bias,
                                                   const float* __restrict__ extra,
                                                   float* __restrict__ C,
                                                   int Mrows, int Kdim, int Ncols)
{
    __shared__ float As[16][64];
    __shared__ float Bs[16][64];
    const int tid = threadIdx.x;
    const int tx = tid & 15, ty = tid >> 4;
    const int m0 = blockIdx.y << 6, n0 = blockIdx.x << 6;
    float acc[4][4] = {};
    for (int k0 = 0; k0 < Kdim; k0 += 16) {
#pragma unroll
        for (int i = 0; i < 4; ++i) {
            const int e = tid + (i << 8);
            const int col = e & 63, row = e >> 6;
            const int gk = k0 + row;
            As[row][col] = (gk < Kdim) ? A[(size_t)(m0 + col) * Kdim + gk] : 0.f;
            Bs[row][col] = (gk < Kdim) ? Bw[(size_t)gk * Ncols + n0 + col] : 0.f;
        }
        __syncthreads();
#pragma unroll
        for (int kk = 0; kk < 16; ++kk) {
            const float4 ra = *(const float4*)(&As[kk][ty << 2]);
            const float4 rb = *(const float4*)(&Bs[kk][tx << 2]);
            const float av[4] = {ra.x, ra.y, ra.z, ra.w};
            const float bv[4] = {rb.x, rb.y, rb.z, rb.w};
#pragma unroll
            for (int ii = 0; ii < 4; ++ii)
#pragma unroll
                for (int jj = 0; jj < 4; ++jj)
                    acc[ii][jj] = fmaf(av[ii], bv[jj], acc[ii][jj]);
        }
        __syncthreads();
    }
#pragma unroll
    for (int ii = 0; ii < 4; ++ii) {
        const int gm = m0 + (ty << 2) + ii;
#pragma unroll
        for (int jj = 0; jj < 4; ++jj) {
            const int gn = n0 + (tx << 2) + jj;
            float v = acc[ii][jj] + bias[gn];
            if (EPI == 1) v = fmaxf(v, 0.f);
            if (EPI == 2) v += extra[(size_t)gm * Ncols + gn];
            C[(size_t)gm * Ncols + gn] = v;
        }
    }
}

// ------------------------- BN + max over k -------------------------
__global__ __launch_bounds__(256) void bnmax_kernel(const float* __restrict__ h,
                                                    const float* __restrict__ g,
                                                    const float* __restrict__ be,
                                                    const float* __restrict__ mu,
                                                    const float* __restrict__ var,
                                                    float* __restrict__ f)
{
    const int r = blockIdx.x;          // 0..B*M-1
    const int m = r & (MCENT - 1);
    const int c = threadIdx.x;
    const float inv = g[m] / sqrtf(var[m] + 1e-5f);
    const float shift = be[m] - mu[m] * inv;
    const size_t base = (size_t)r * 3 * AD + c;
    const float v0 = fmaxf(h[base] * inv + shift, 0.f);
    const float v1 = fmaxf(h[base + AD] * inv + shift, 0.f);
    const float v2 = fmaxf(h[base + 2 * AD] * inv + shift, 0.f);
    f[(size_t)r * AD + c] = fmaxf(v0, fmaxf(v1, v2));
}

// ------------------------- W_q - W_k precompute --------------------
__global__ void wdiff_kernel(const float* __restrict__ Wq, const float* __restrict__ bq,
                             const float* __restrict__ Wk, const float* __restrict__ bk,
                             float* __restrict__ Wqk, float* __restrict__ bqk)
{
    const int i = blockIdx.x * blockDim.x + threadIdx.x;
    if (i < AD * AD) Wqk[i] = Wq[i] - Wk[i];
    if (i < AD) bqk[i] = bq[i] - bk[i];
}

// --------------------------- softmax -------------------------------
__global__ __launch_bounds__(256) void softmax_kernel(float* __restrict__ s)
{
    const int r = blockIdx.x;
    const int c = threadIdx.x;
    const int lane = c & 63, w = c >> 6;
    float v = s[(size_t)r * AD + c];
    float mx = v;
#pragma unroll
    for (int off = 1; off < 64; off <<= 1) mx = fmaxf(mx, __shfl_xor(mx, off, 64));
    __shared__ float sm[4];
    __shared__ float ss[4];
    if (lane == 0) sm[w] = mx;
    __syncthreads();
    mx = fmaxf(fmaxf(sm[0], sm[1]), fmaxf(sm[2], sm[3]));
    const float e = expf(v - mx);
    float sum = e;
#pragma unroll
    for (int off = 1; off < 64; off <<= 1) sum += __shfl_xor(sum, off, 64);
    if (lane == 0) ss[w] = sum;
    __syncthreads();
    sum = ss[0] + ss[1] + ss[2] + ss[3];
    s[(size_t)r * AD + c] = e / sum;
}

// --------------------------- w * v ---------------------------------
__global__ void mul_kernel(const float* __restrict__ w, float* __restrict__ v, int n)
{
    for (int i = blockIdx.x * blockDim.x + threadIdx.x; i < n; i += gridDim.x * blockDim.x)
        v[i] = w[i] * v[i];
}

// ---------------------------- launch -------------------------------
extern "C" void kernel_launch(void* const* d_in, const int* in_sizes, int n_in,
                              void* d_out, int out_size, void* d_ws, size_t ws_size,
                              hipStream_t stream)
{
    const float* x       = (const float*)d_in[0];
    const float* spatial = (const float*)d_in[1];
    const float* W_sa  = (const float*)d_in[2];
    const float* b_sa  = (const float*)d_in[3];
    const float* gamma = (const float*)d_in[4];
    const float* beta  = (const float*)d_in[5];
    const float* mean  = (const float*)d_in[6];
    const float* var   = (const float*)d_in[7];
    const float* W_in  = (const float*)d_in[8];
    const float* b_in  = (const float*)d_in[9];
    const float* W_q   = (const float*)d_in[10];
    const float* b_q   = (const float*)d_in[11];
    const float* W_k   = (const float*)d_in[12];
    const float* b_k   = (const float*)d_in[13];
    const float* W_v   = (const float*)d_in[14];
    const float* b_v   = (const float*)d_in[15];
    const float* W_w1  = (const float*)d_in[16];
    const float* b_w1  = (const float*)d_in[17];
    const float* W_w2  = (const float*)d_in[18];
    const float* b_w2  = (const float*)d_in[19];
    const float* W_out = (const float*)d_in[20];
    const float* b_out = (const float*)d_in[21];

    float* ws = (float*)d_ws;
    size_t o = 0;
    int* idxs = (int*)(ws + o); o += BATCH * MCENT;                 // 8192
    int* nn   = (int*)(ws + o); o += BATCH * MCENT * 3;             // 24576
    float* Wqk = ws + o; o += AD * AD;
    float* bqk = ws + o; o += AD;
    float* Asa = ws + o; o += (size_t)BATCH * MCENT * 3 * 69;       // 1695744
    float* h   = ws + o; o += (size_t)BATCH * MCENT * 3 * AD;       // 6291456
    float* f   = ws + o; o += (size_t)BATCH * MCENT * AD;           // 2097152
    float* u   = ws + o; o += (size_t)BATCH * MCENT * AD;           // 2097152
    // reuse h region after bnmax: t, qd, v ; reuse qd region for sgm
    float* t   = h;
    float* qd  = h + (size_t)BATCH * MCENT * AD;
    float* v   = h + (size_t)2 * BATCH * MCENT * AD;
    float* sgm = qd;

    float* outp = (float*)d_out;
    float* cent = outp + (size_t)BATCH * MCENT * AD;

    const int ROWS = BATCH * MCENT;          // 8192
    const int HROWS = ROWS * 3;              // 24576

    fps_kernel<<<BATCH, FPS_T, 0, stream>>>(spatial, idxs);
    knn_kernel<<<BATCH * 64, 512, 0, stream>>>(spatial, idxs, nn);
    gather_kernel<<<ROWS, 256, 0, stream>>>(x, spatial, idxs, nn, Asa, cent);
    wdiff_kernel<<<(AD * AD + 255) / 256, 256, 0, stream>>>(W_q, b_q, W_k, b_k, Wqk, bqk);

    gemm_kernel<0><<<dim3(AD / 64, HROWS / 64), 256, 0, stream>>>(Asa, W_sa, b_sa, nullptr, h, HROWS, 69, AD);
    bnmax_kernel<<<ROWS, 256, 0, stream>>>(h, gamma, beta, mean, var, f);
    gemm_kernel<0><<<dim3(AD / 64, ROWS / 64), 256, 0, stream>>>(f, W_in, b_in, nullptr, t, ROWS, AD, AD);
    gemm_kernel<0><<<dim3(AD / 64, ROWS / 64), 256, 0, stream>>>(t, Wqk, bqk, nullptr, qd, ROWS, AD, AD);
    gemm_kernel<0><<<dim3(AD / 64, ROWS / 64), 256, 0, stream>>>(t, W_v, b_v, nullptr, v, ROWS, AD, AD);
    gemm_kernel<1><<<dim3(AD / 64, ROWS / 64), 256, 0, stream>>>(qd, W_w1, b_w1, nullptr, u, ROWS, AD, AD);
    gemm_kernel<0><<<dim3(AD / 64, ROWS / 64), 256, 0, stream>>>(u, W_w2, b_w2, nullptr, sgm, ROWS, AD, AD);
    softmax_kernel<<<ROWS, 256, 0, stream>>>(sgm);
    mul_kernel<<<2048, 256, 0, stream>>>(sgm, v, ROWS * AD);
    gemm_kernel<2><<<dim3(AD / 64, ROWS / 64), 256, 0, stream>>>(v, W_out, b_out, f, outp, ROWS, AD, AD);
}

// Round 6
// 7784.197 us; speedup vs baseline: 1.4549x; 1.0450x over previous
//
#include <hip/hip_runtime.h>
#include <math.h>

#define NPTS 8192
#define BATCH 2
#define MCENT 4096
#define FD 64
#define SD 5
#define AD 256

typedef float f32x2 __attribute__((ext_vector_type(2)));

// ----------------------------- FPS ---------------------------------
// One block per batch, 1024 threads, 8 points/thread.
// Coords c0..c3 of all points in 128KB LDS; c4 + running dists in regs.
// r5: signed-i64 keys (hi=float bits of dist, lo=~idx) — monotone for
// dist>=0, masked -inf goes negative, tie -> lowest idx; ONE barrier per
// iteration (parity-double-buffered skey + all-lane 16-slot broadcast
// read + 4-step butterfly); pivot c4 global load issued early.
#define FPS_T 1024
#define FPS_PAIRS 4

__global__ __launch_bounds__(FPS_T) void fps_kernel(const float* __restrict__ spatial,
                                                    int* __restrict__ idxs)
{
#pragma clang fp contract(off)
    const int b = blockIdx.x;
    const int tid = threadIdx.x;
    const float* sp = spatial + (size_t)b * NPTS * SD;
    int* out = idxs + (size_t)b * MCENT;

    __shared__ float cs0[NPTS];              // 32 KB
    __shared__ float cs1[NPTS];              // 32 KB
    __shared__ float cs2[NPTS];              // 32 KB
    __shared__ float cs3[NPTS];              // 32 KB
    __shared__ long long skey[2][16];        // parity double-buffered

    for (int e = tid; e < NPTS; e += FPS_T) {
        cs0[e] = sp[(size_t)e * SD + 0];
        cs1[e] = sp[(size_t)e * SD + 1];
        cs2[e] = sp[(size_t)e * SD + 2];
        cs3[e] = sp[(size_t)e * SD + 3];
    }
    f32x2 c4p[FPS_PAIRS];
    f32x2 d2[FPS_PAIRS];
#pragma unroll
    for (int q = 0; q < FPS_PAIRS; ++q) {
        const int p0 = tid + ((2 * q) << 10);
        c4p[q].x = sp[(size_t)p0 * SD + 4];
        c4p[q].y = sp[(size_t)(p0 + 1024) * SD + 4];
        d2[q].x = INFINITY; d2[q].y = INFINITY;
    }
    // pin c4 (8 regs, far under budget) so it is neither re-loaded nor spilled
#pragma unroll
    for (int q = 0; q < FPS_PAIRS; ++q)
        asm volatile("" : "+v"(c4p[q].x), "+v"(c4p[q].y));

    if (tid == 0) { d2[0].x = -INFINITY; out[0] = 0; }   // point 0 pre-selected

    float l0 = sp[0], l1 = sp[1], l2 = sp[2], l3 = sp[3], l4 = sp[4];
    const int lane = tid & 63, wid = tid >> 6;
    __syncthreads();

    for (int i = 1; i < MCENT; ++i) {
        const int par = i & 1;
        const f32x2 L0 = {l0, l0}, L1 = {l1, l1}, L2 = {l2, l2},
                    L3 = {l3, l3}, L4 = {l4, l4};
        long long best = 0x8000000000000000LL;
#pragma unroll
        for (int q = 0; q < FPS_PAIRS; ++q) {
            const int p0 = tid + ((2 * q) << 10);
            const int p1 = p0 + 1024;
            const f32x2 v0 = { cs0[p0], cs0[p1] };
            const f32x2 v1 = { cs1[p0], cs1[p1] };
            const f32x2 v2 = { cs2[p0], cs2[p1] };
            const f32x2 v3 = { cs3[p0], cs3[p1] };
            // exact numpy order: ((((d0^2+d1^2)+d2^2)+d3^2)+d4^2
            f32x2 dx = v0 - L0;     f32x2 s = dx * dx;
            f32x2 dy = v1 - L1;     s = s + dy * dy;
            f32x2 dz = v2 - L2;     s = s + dz * dz;
            f32x2 dw = v3 - L3;     s = s + dw * dw;
            f32x2 du = c4p[q] - L4; s = s + du * du;
            const f32x2 nd = __builtin_elementwise_min(d2[q], s); // -inf absorbing
            d2[q] = nd;
            // signed-i64 key: hi = float bits (monotone for >=0, masked<0), lo = ~idx
            const long long k0 = ((long long)__float_as_int(nd.x) << 32)
                                 | (unsigned long long)(unsigned)(~p0);
            const long long k1 = ((long long)__float_as_int(nd.y) << 32)
                                 | (unsigned long long)(unsigned)(~p1);
            if (k0 > best) best = k0;
            if (k1 > best) best = k1;
        }
        // 64-lane butterfly max (i64)
#pragma unroll
        for (int off = 1; off < 64; off <<= 1) {
            const long long o = __shfl_xor(best, off, 64);
            if (o > best) best = o;
        }
        if (lane == 0) skey[par][wid] = best;
        __syncthreads();
        // every lane reads one of the 16 wave results (broadcast within
        // 16-lane groups), 4-step butterfly -> all lanes hold global max
        long long k = skey[par][lane & 15];
#pragma unroll
        for (int off = 1; off < 16; off <<= 1) {
            const long long o = __shfl_xor(k, off, 64);
            if (o > k) k = o;
        }
        const int gidx = ~((int)(unsigned)k);      // low word = ~idx
        if (tid == 0) out[i] = gidx;
        // mask the selected point (static indices only)
        const int dlt = gidx - tid;
#pragma unroll
        for (int q = 0; q < FPS_PAIRS; ++q) {
            if (dlt == ((2 * q) << 10))     d2[q].x = -INFINITY;
            if (dlt == ((2 * q + 1) << 10)) d2[q].y = -INFINITY;
        }
        // pivot coords: c4 from global issued EARLY (latency hides under
        // mask update + next-iter partial sums), c0..c3 from LDS broadcast
        const int su = __builtin_amdgcn_readfirstlane(gidx);
        l4 = sp[(size_t)su * SD + 4];
        l0 = cs0[su]; l1 = cs1[su]; l2 = cs2[su]; l3 = cs3[su];
    }
}

// ----------------------------- KNN ---------------------------------
// Stable top-4 smallest (d, idx) per centroid; self forced to -1.0.
// Block: 512 threads = 64 centroids x 8 partial scanners. Grid: B*64.
#define KPARTS 8
__global__ __launch_bounds__(512) void knn_kernel(const float* __restrict__ spatial,
                                                  const int* __restrict__ idxs,
                                                  int* __restrict__ nn)
{
#pragma clang fp contract(off)
    const int blk = blockIdx.x;
    const int b = blk >> 6;
    const int grp = blk & 63;
    const int tid = threadIdx.x;
    const int lc = tid >> 3;      // local centroid 0..63
    const int part = tid & 7;
    const float* sp = spatial + (size_t)b * NPTS * SD;
    const int cid = (grp << 6) + lc;
    const int ctr = idxs[b * MCENT + cid];
    const float c0 = sp[(size_t)ctr * SD + 0], c1 = sp[(size_t)ctr * SD + 1],
                c2 = sp[(size_t)ctr * SD + 2], c3 = sp[(size_t)ctr * SD + 3],
                c4 = sp[(size_t)ctr * SD + 4];

    float bd[4] = {INFINITY, INFINITY, INFINITY, INFINITY};
    int   bi[4] = {0x7fffffff, 0x7fffffff, 0x7fffffff, 0x7fffffff};

    __shared__ float tile[2048 * SD];            // 40 KB
    __shared__ float md[64][KPARTS][4];          // 8 KB
    __shared__ int   mi[64][KPARTS][4];          // 8 KB

    for (int t0 = 0; t0 < NPTS; t0 += 2048) {
        __syncthreads();
        for (int e = tid; e < 2048 * SD; e += 512) tile[e] = sp[(size_t)t0 * SD + e];
        __syncthreads();
        for (int p = part; p < 2048; p += KPARTS) {
            const int gp = t0 + p;
            float x0 = tile[p * SD + 0] - c0; float d = x0 * x0;
            float x1 = tile[p * SD + 1] - c1; d = d + x1 * x1;
            float x2 = tile[p * SD + 2] - c2; d = d + x2 * x2;
            float x3 = tile[p * SD + 3] - c3; d = d + x3 * x3;
            float x4 = tile[p * SD + 4] - c4; d = d + x4 * x4;
            if (gp == ctr) d = -1.0f;
            const bool lt0 = (d < bd[0]) || (d == bd[0] && gp < bi[0]);
            const bool lt1 = (d < bd[1]) || (d == bd[1] && gp < bi[1]);
            const bool lt2 = (d < bd[2]) || (d == bd[2] && gp < bi[2]);
            const bool lt3 = (d < bd[3]) || (d == bd[3] && gp < bi[3]);
            if (lt3) {
                bd[3] = lt2 ? bd[2] : d;  bi[3] = lt2 ? bi[2] : gp;
                if (lt2) {
                    bd[2] = lt1 ? bd[1] : d;  bi[2] = lt1 ? bi[1] : gp;
                    if (lt1) {
                        bd[1] = lt0 ? bd[0] : d;  bi[1] = lt0 ? bi[0] : gp;
                        if (lt0) { bd[0] = d; bi[0] = gp; }
                    }
                }
            }
        }
    }
#pragma unroll
    for (int s = 0; s < 4; ++s) { md[lc][part][s] = bd[s]; mi[lc][part][s] = bi[s]; }
    __syncthreads();
    if (part == 0) {
        int ptr[KPARTS] = {0, 0, 0, 0, 0, 0, 0, 0};
        int outi[4];
        for (int s = 0; s < 4; ++s) {
            float bestd = INFINITY; int besti = 0x7fffffff; int bl = 0;
            for (int l = 0; l < KPARTS; ++l) {
                const int pl = ptr[l];
                if (pl < 4) {
                    const float dv = md[lc][l][pl];
                    const int   iv = mi[lc][l][pl];
                    if (dv < bestd || (dv == bestd && iv < besti)) { bestd = dv; besti = iv; bl = l; }
                }
            }
            ptr[bl]++;
            outi[s] = besti;
        }
        int* o = nn + ((size_t)b * MCENT + cid) * 3;
        o[0] = outi[1]; o[1] = outi[2]; o[2] = outi[3];   // skip self
    }
}

// --------------------------- gather --------------------------------
// Builds A_sa [B*M*3, 69] = [nbr_feat | rel] and writes centroids to d_out.
__global__ __launch_bounds__(256) void gather_kernel(const float* __restrict__ x,
                                                     const float* __restrict__ spatial,
                                                     const int* __restrict__ idxs,
                                                     const int* __restrict__ nn,
                                                     float* __restrict__ Asa,
                                                     float* __restrict__ cent_out)
{
    const int r = blockIdx.x;           // 0..B*M-1
    const int b = r >> 12;
    const int tid = threadIdx.x;
    const float* sp = spatial + (size_t)b * NPTS * SD;
    const float* xb = x + (size_t)b * NPTS * FD;
    const int ctr = idxs[r];
    __shared__ int nnk[3];
    if (tid < 3) nnk[tid] = nn[(size_t)r * 3 + tid];
    __syncthreads();
    if (tid < 192) {
        const int k = tid >> 6, c = tid & 63;
        Asa[((size_t)r * 3 + k) * 69 + c] = xb[(size_t)nnk[k] * FD + c];
    } else if (tid < 207) {
        const int e = tid - 192; const int k = e / 5, c = e % 5;
        Asa[((size_t)r * 3 + k) * 69 + 64 + c] =
            sp[(size_t)nnk[k] * SD + c] - sp[(size_t)ctr * SD + c];
    } else if (tid < 212) {
        const int c = tid - 207;
        cent_out[(size_t)r * SD + c] = sp[(size_t)ctr * SD + c];
    }
}

// ---------------------------- GEMM ---------------------------------
// C[M,N] = A[M,K] @ B[K,N] + bias ; EPI: 0 none, 1 relu, 2 +extra
template<int EPI>
__global__ __launch_bounds__(256) void gemm_kernel(const float* __restrict__ A,
                                                   const float* __restrict__ Bw,
                                                   const float* __restrict__ bias,
                                                   const float* __restrict__ extra,
                                                   float* __restrict__ C,
                                                   int Mrows, int Kdim, int Ncols)
{
    __shared__ float As[16][64];
    __shared__ float Bs[16][64];
    const int tid = threadIdx.x;
    const int tx = tid & 15, ty = tid >> 4;
    const int m0 = blockIdx.y << 6, n0 = blockIdx.x << 6;
    float acc[4][4] = {};
    for (int k0 = 0; k0 < Kdim; k0 += 16) {
#pragma unroll
        for (int i = 0; i < 4; ++i) {
            const int e = tid + (i << 8);
            const int col = e & 63, row = e >> 6;
            const int gk = k0 + row;
            As[row][col] = (gk < Kdim) ? A[(size_t)(m0 + col) * Kdim + gk] : 0.f;
            Bs[row][col] = (gk < Kdim) ? Bw[(size_t)gk * Ncols + n0 + col] : 0.f;
        }
        __syncthreads();
#pragma unroll
        for (int kk = 0; kk < 16; ++kk) {
            const float4 ra = *(const float4*)(&As[kk][ty << 2]);
            const float4 rb = *(const float4*)(&Bs[kk][tx << 2]);
            const float av[4] = {ra.x, ra.y, ra.z, ra.w};
            const float bv[4] = {rb.x, rb.y, rb.z, rb.w};
#pragma unroll
            for (int ii = 0; ii < 4; ++ii)
#pragma unroll
                for (int jj = 0; jj < 4; ++jj)
                    acc[ii][jj] = fmaf(av[ii], bv[jj], acc[ii][jj]);
        }
        __syncthreads();
    }
#pragma unroll
    for (int ii = 0; ii < 4; ++ii) {
        const int gm = m0 + (ty << 2) + ii;
#pragma unroll
        for (int jj = 0; jj < 4; ++jj) {
            const int gn = n0 + (tx << 2) + jj;
            float v = acc[ii][jj] + bias[gn];
            if (EPI == 1) v = fmaxf(v, 0.f);
            if (EPI == 2) v += extra[(size_t)gm * Ncols + gn];
            C[(size_t)gm * Ncols + gn] = v;
        }
    }
}

// ------------------------- BN + max over k -------------------------
__global__ __launch_bounds__(256) void bnmax_kernel(const float* __restrict__ h,
                                                    const float* __restrict__ g,
                                                    const float* __restrict__ be,
                                                    const float* __restrict__ mu,
                                                    const float* __restrict__ var,
                                                    float* __restrict__ f)
{
    const int r = blockIdx.x;          // 0..B*M-1
    const int m = r & (MCENT - 1);
    const int c = threadIdx.x;
    const float inv = g[m] / sqrtf(var[m] + 1e-5f);
    const float shift = be[m] - mu[m] * inv;
    const size_t base = (size_t)r * 3 * AD + c;
    const float v0 = fmaxf(h[base] * inv + shift, 0.f);
    const float v1 = fmaxf(h[base + AD] * inv + shift, 0.f);
    const float v2 = fmaxf(h[base + 2 * AD] * inv + shift, 0.f);
    f[(size_t)r * AD + c] = fmaxf(v0, fmaxf(v1, v2));
}

// ------------------------- W_q - W_k precompute --------------------
__global__ void wdiff_kernel(const float* __restrict__ Wq, const float* __restrict__ bq,
                             const float* __restrict__ Wk, const float* __restrict__ bk,
                             float* __restrict__ Wqk, float* __restrict__ bqk)
{
    const int i = blockIdx.x * blockDim.x + threadIdx.x;
    if (i < AD * AD) Wqk[i] = Wq[i] - Wk[i];
    if (i < AD) bqk[i] = bq[i] - bk[i];
}

// --------------------------- softmax -------------------------------
__global__ __launch_bounds__(256) void softmax_kernel(float* __restrict__ s)
{
    const int r = blockIdx.x;
    const int c = threadIdx.x;
    const int lane = c & 63, w = c >> 6;
    float v = s[(size_t)r * AD + c];
    float mx = v;
#pragma unroll
    for (int off = 1; off < 64; off <<= 1) mx = fmaxf(mx, __shfl_xor(mx, off, 64));
    __shared__ float sm[4];
    __shared__ float ss[4];
    if (lane == 0) sm[w] = mx;
    __syncthreads();
    mx = fmaxf(fmaxf(sm[0], sm[1]), fmaxf(sm[2], sm[3]));
    const float e = expf(v - mx);
    float sum = e;
#pragma unroll
    for (int off = 1; off < 64; off <<= 1) sum += __shfl_xor(sum, off, 64);
    if (lane == 0) ss[w] = sum;
    __syncthreads();
    sum = ss[0] + ss[1] + ss[2] + ss[3];
    s[(size_t)r * AD + c] = e / sum;
}

// --------------------------- w * v ---------------------------------
__global__ void mul_kernel(const float* __restrict__ w, float* __restrict__ v, int n)
{
    for (int i = blockIdx.x * blockDim.x + threadIdx.x; i < n; i += gridDim.x * blockDim.x)
        v[i] = w[i] * v[i];
}

// ---------------------------- launch -------------------------------
extern "C" void kernel_launch(void* const* d_in, const int* in_sizes, int n_in,
                              void* d_out, int out_size, void* d_ws, size_t ws_size,
                              hipStream_t stream)
{
    const float* x       = (const float*)d_in[0];
    const float* spatial = (const float*)d_in[1];
    const float* W_sa  = (const float*)d_in[2];
    const float* b_sa  = (const float*)d_in[3];
    const float* gamma = (const float*)d_in[4];
    const float* beta  = (const float*)d_in[5];
    const float* mean  = (const float*)d_in[6];
    const float* var   = (const float*)d_in[7];
    const float* W_in  = (const float*)d_in[8];
    const float* b_in  = (const float*)d_in[9];
    const float* W_q   = (const float*)d_in[10];
    const float* b_q   = (const float*)d_in[11];
    const float* W_k   = (const float*)d_in[12];
    const float* b_k   = (const float*)d_in[13];
    const float* W_v   = (const float*)d_in[14];
    const float* b_v   = (const float*)d_in[15];
    const float* W_w1  = (const float*)d_in[16];
    const float* b_w1  = (const float*)d_in[17];
    const float* W_w2  = (const float*)d_in[18];
    const float* b_w2  = (const float*)d_in[19];
    const float* W_out = (const float*)d_in[20];
    const float* b_out = (const float*)d_in[21];

    float* ws = (float*)d_ws;
    size_t o = 0;
    int* idxs = (int*)(ws + o); o += BATCH * MCENT;                 // 8192
    int* nn   = (int*)(ws + o); o += BATCH * MCENT * 3;             // 24576
    float* Wqk = ws + o; o += AD * AD;
    float* bqk = ws + o; o += AD;
    float* Asa = ws + o; o += (size_t)BATCH * MCENT * 3 * 69;       // 1695744
    float* h   = ws + o; o += (size_t)BATCH * MCENT * 3 * AD;       // 6291456
    float* f   = ws + o; o += (size_t)BATCH * MCENT * AD;           // 2097152
    float* u   = ws + o; o += (size_t)BATCH * MCENT * AD;           // 2097152
    // reuse h region after bnmax: t, qd, v ; reuse qd region for sgm
    float* t   = h;
    float* qd  = h + (size_t)BATCH * MCENT * AD;
    float* v   = h + (size_t)2 * BATCH * MCENT * AD;
    float* sgm = qd;

    float* outp = (float*)d_out;
    float* cent = outp + (size_t)BATCH * MCENT * AD;

    const int ROWS = BATCH * MCENT;          // 8192
    const int HROWS = ROWS * 3;              // 24576

    fps_kernel<<<BATCH, FPS_T, 0, stream>>>(spatial, idxs);
    knn_kernel<<<BATCH * 64, 512, 0, stream>>>(spatial, idxs, nn);
    gather_kernel<<<ROWS, 256, 0, stream>>>(x, spatial, idxs, nn, Asa, cent);
    wdiff_kernel<<<(AD * AD + 255) / 256, 256, 0, stream>>>(W_q, b_q, W_k, b_k, Wqk, bqk);

    gemm_kernel<0><<<dim3(AD / 64, HROWS / 64), 256, 0, stream>>>(Asa, W_sa, b_sa, nullptr, h, HROWS, 69, AD);
    bnmax_kernel<<<ROWS, 256, 0, stream>>>(h, gamma, beta, mean, var, f);
    gemm_kernel<0><<<dim3(AD / 64, ROWS / 64), 256, 0, stream>>>(f, W_in, b_in, nullptr, t, ROWS, AD, AD);
    gemm_kernel<0><<<dim3(AD / 64, ROWS / 64), 256, 0, stream>>>(t, Wqk, bqk, nullptr, qd, ROWS, AD, AD);
    gemm_kernel<0><<<dim3(AD / 64, ROWS / 64), 256, 0, stream>>>(t, W_v, b_v, nullptr, v, ROWS, AD, AD);
    gemm_kernel<1><<<dim3(AD / 64, ROWS / 64), 256, 0, stream>>>(qd, W_w1, b_w1, nullptr, u, ROWS, AD, AD);
    gemm_kernel<0><<<dim3(AD / 64, ROWS / 64), 256, 0, stream>>>(u, W_w2, b_w2, nullptr, sgm, ROWS, AD, AD);
    softmax_kernel<<<ROWS, 256, 0, stream>>>(sgm);
    mul_kernel<<<2048, 256, 0, stream>>>(sgm, v, ROWS * AD);
    gemm_kernel<2><<<dim3(AD / 64, ROWS / 64), 256, 0, stream>>>(v, W_out, b_out, f, outp, ROWS, AD, AD);
}